// Round 21
// baseline (62.481 us; speedup 1.0000x reference)
//
#include <hip/hip_runtime.h>
#include <math.h>
#include <stdint.h>

// Router: scores = x @ emb^T [32768 x 64] fp32-accurate, top-2 + 2-way softmax.
//
// Error-free split-bf16 MFMA (rounds 9-20): 3 bf16 limbs per fp32 operand,
// 6 limb-product MFMA passes accumulated in fp32 (~3e-7 error).
// Rounds 19/20 TLP-nulls localize the limiter to the per-CU LDS pipe
// (~53-63k of 106k cyc), dominated by B-frag reads (12 b128 per 16 tokens).
// This round: mfma_f32_32x32x16_bf16 -- wave = 32 tok x 64 exp (2 tiles,
// acc 2x f32x16). Per wave-iter: 4 A + 12 B reads feed 2x the tokens ->
// LDS reads/CU halved (43k -> ~25k cyc), instruction issue ~halved.
// Layouts: A/B row(col)=lane&31, k=(lane>>5)*8+j (generalizes our verified
// 16x16x32 mapping); C/D col=lane&31, row=(reg&3)+8*(reg>>2)+4*(lane>>5)
// (guide m74/m101). Same K-split x2 + staging + vmcnt ledger as round 20.

typedef __attribute__((ext_vector_type(8)))  short short8;
typedef __attribute__((ext_vector_type(16))) float f32x16;

constexpr int HDIM = 1024;
constexpr int NEXP = 64;
constexpr int TPB  = 64;            // tokens per block (2 tiles of 32)
constexpr int NTHREADS = 256;       // 4 waves = 2 token-tiles x 2 K-halves
constexpr int NITER = 16;           // 32-k chunks per K-half

__device__ __forceinline__ uint32_t cvtpk_bf16(float lo, float hi) {
    uint32_t r;
    asm("v_cvt_pk_bf16_f32 %0, %1, %2" : "=v"(r) : "v"(lo), "v"(hi));
    return r;
}

// RNE 3-limb bf16 split of 8 fp32 values; outputs packed frag words.
__device__ __forceinline__ void split8(const float4& A, const float4& B,
                                       uint32_t w0[4], uint32_t w1[4],
                                       uint32_t w2[4])
{
    const float p[8] = {A.x, A.y, A.z, A.w, B.x, B.y, B.z, B.w};
#pragma unroll
    for (int m = 0; m < 4; ++m) {
        const float lo = p[2 * m], hi = p[2 * m + 1];
        const uint32_t c0 = cvtpk_bf16(lo, hi);
        const float l0 = __uint_as_float(c0 << 16);
        const float h0 = __uint_as_float(c0 & 0xFFFF0000u);
        const float rl = lo - l0, rh = hi - h0;         // exact
        const uint32_t c1 = cvtpk_bf16(rl, rh);
        const float l1 = __uint_as_float(c1 << 16);
        const float h1 = __uint_as_float(c1 & 0xFFFF0000u);
        const uint32_t c2 = cvtpk_bf16(rl - l1, rh - h1);
        w0[m] = c0; w1[m] = c1; w2[m] = c2;
    }
}

__device__ __forceinline__ short8 frag_of(uint32_t a, uint32_t b,
                                          uint32_t c, uint32_t d) {
    union { uint4 u; short8 s; } cv;
    cv.u = make_uint4(a, b, c, d);
    return cv.s;
}
__device__ __forceinline__ short8 frag_of4(const uint4& v) {
    union { uint4 u; short8 s; } cv;
    cv.u = v;
    return cv.s;
}

// prepack for 32x32x16 B-frags, chunk-contiguous:
// wsb[((ch*2+s)*6 + t*3 + L)*64 + lane] =
//   limb L of emb[32t + (lane&31)][ch*32 + s*16 + (lane>>5)*8 .. +7]
__global__ __launch_bounds__(256)
void prepack_kernel(const float* __restrict__ emb, uint4* __restrict__ wsb)
{
    const int f2   = blockIdx.x * 256 + threadIdx.x;   // 0..8191
    const int lane = f2 & 63;
    const int t    = (f2 >> 6) & 1;
    const int s    = (f2 >> 7) & 1;
    const int ch   = f2 >> 8;                          // 0..31
    const int e    = 32 * t + (lane & 31);
    const int k0   = ch * 32 + s * 16 + (lane >> 5) * 8;
    const float4 A = *(const float4*)(emb + (size_t)e * HDIM + k0);
    const float4 B = *(const float4*)(emb + (size_t)e * HDIM + k0 + 4);
    uint32_t w0[4], w1[4], w2[4];
    split8(A, B, w0, w1, w2);
    const int ob = ((ch * 2 + s) * 6 + t * 3) * 64 + lane;
    wsb[ob]       = make_uint4(w0[0], w0[1], w0[2], w0[3]);
    wsb[ob + 64]  = make_uint4(w1[0], w1[1], w1[2], w1[3]);
    wsb[ob + 128] = make_uint4(w2[0], w2[1], w2[2], w2[3]);
}

__global__ __launch_bounds__(NTHREADS, 2)
void router_kernel(const float* __restrict__ x,
                   const uint4* __restrict__ wsb,
                   float* __restrict__ out)
{
    // 57344 B -> 2 blocks/CU. Epilogue buffers alias into xs / bs.
    __shared__ float4 xs[2][2][TPB][8];  // 32 KiB [buf][half][token][quad]
    __shared__ uint4  bs[2][768];        // 24 KiB [half][chunk image]

    const int tid  = threadIdx.x;
    const int lane = tid & 63;
    const int W    = tid >> 6;          // wave 0..3
    const int m    = W & 1;             // token tile: tokens [32m, 32m+32)
    const int h    = W >> 1;            // K-half: chunks [16h, 16h+16)
    const int tok0 = blockIdx.x * TPB;
    const int rw   = lane & 31;         // A row / B col / C col
    const int g    = lane >> 5;         // k-subgroup

    // x stage for both halves' chunk C: 1024 float4, 4 loads/thread.
    // XOR swizzle (q^(r&7)) folded into global source; LDS dest linear.
#define STAGE_X(P, C)                                                          \
    do {                                                                       \
        _Pragma("unroll")                                                      \
        for (int jj = 0; jj < 4; ++jj) {                                       \
            const int g_  = jj * NTHREADS + tid;                               \
            const int hh_ = g_ >> 9, gg_ = g_ & 511;                           \
            const int r_ = gg_ >> 3, q_ = gg_ & 7;                             \
            const float* src = x + (size_t)(tok0 + r_) * HDIM                  \
                                 + (hh_ * 16 + (C)) * 32                       \
                                 + ((q_ ^ (r_ & 7)) * 4);                      \
            __builtin_amdgcn_global_load_lds(                                  \
                (const __attribute__((address_space(1))) void*)src,            \
                (__attribute__((address_space(3))) void*)&xs[P][hh_][r_][q_],  \
                16, 0, 0);                                                     \
        }                                                                      \
    } while (0)

    // B stage for both halves' chunk C: 1536 uint4, 6 loads/thread.
#define STAGE_B(C)                                                             \
    do {                                                                       \
        _Pragma("unroll")                                                      \
        for (int jj = 0; jj < 6; ++jj) {                                       \
            const int f_  = jj * NTHREADS + tid;                               \
            const int hh_ = (f_ >= 768) ? 1 : 0;                               \
            const int of_ = f_ - hh_ * 768;                                    \
            __builtin_amdgcn_global_load_lds(                                  \
                (const __attribute__((address_space(1))) void*)                \
                    (wsb + (size_t)(hh_ * 16 + (C)) * 768 + of_),              \
                (__attribute__((address_space(3))) void*)&bs[hh_][of_],        \
                16, 0, 0);                                                     \
        }                                                                      \
    } while (0)

    // acc[t]: tokens [32m,+32) x experts [32t,+32), partial over K-half h.
    f32x16 acc0 = {0,0,0,0,0,0,0,0,0,0,0,0,0,0,0,0};
    f32x16 acc1 = {0,0,0,0,0,0,0,0,0,0,0,0,0,0,0,0};

    STAGE_X(0, 0);
    STAGE_B(0);
    STAGE_X(1, 1);

#pragma unroll 1
    for (int c = 0; c < NITER; ++c) {
        // Ledger: top of iter c outstanding = B(c)[6] + X(c+1)[4] ->
        // vmcnt(4) retires B(c) (and older X), keeps X(c+1) in flight.
        if (c < NITER - 1) {
            asm volatile("s_waitcnt vmcnt(4)" ::: "memory");
        } else {
            asm volatile("s_waitcnt vmcnt(0)" ::: "memory");
        }
        __builtin_amdgcn_s_barrier();
        asm volatile("" ::: "memory");

        const int p   = c & 1;
        const int row = 32 * m + rw;
#pragma unroll
        for (int s = 0; s < 2; ++s) {          // k = s*16 .. s*16+15
            const int qb = s * 4 + g * 2;      // lane's 8 fp32 = quads qb,qb+1
            const float4 a0 = xs[p][h][row][(qb)     ^ (rw & 7)];
            const float4 a1 = xs[p][h][row][(qb + 1) ^ (rw & 7)];

            uint32_t wa0[4], wa1[4], wa2[4];
            split8(a0, a1, wa0, wa1, wa2);
            const short8 fA0 = frag_of(wa0[0], wa0[1], wa0[2], wa0[3]);
            const short8 fA1 = frag_of(wa1[0], wa1[1], wa1[2], wa1[3]);
            const short8 fA2 = frag_of(wa2[0], wa2[1], wa2[2], wa2[3]);

#pragma unroll
            for (int t = 0; t < 2; ++t) {
                const int bb = (s * 6 + t * 3) * 64 + lane;
                const short8 fb0 = frag_of4(bs[h][bb]);
                const short8 fb1 = frag_of4(bs[h][bb + 64]);
                const short8 fb2 = frag_of4(bs[h][bb + 128]);

                f32x16 a = t ? acc1 : acc0;
                a = __builtin_amdgcn_mfma_f32_32x32x16_bf16(fA2, fb0, a, 0,0,0);
                a = __builtin_amdgcn_mfma_f32_32x32x16_bf16(fA0, fb2, a, 0,0,0);
                a = __builtin_amdgcn_mfma_f32_32x32x16_bf16(fA1, fb1, a, 0,0,0);
                a = __builtin_amdgcn_mfma_f32_32x32x16_bf16(fA1, fb0, a, 0,0,0);
                a = __builtin_amdgcn_mfma_f32_32x32x16_bf16(fA0, fb1, a, 0,0,0);
                a = __builtin_amdgcn_mfma_f32_32x32x16_bf16(fA0, fb0, a, 0,0,0);
                if (t) acc1 = a; else acc0 = a;
            }
        }

        __builtin_amdgcn_s_barrier();   // all waves done reading bs / xs[p]
        asm volatile("" ::: "memory");
        if (c + 1 < NITER) STAGE_B(c + 1);
        if (c + 2 < NITER) STAGE_X(p, c + 2);   // xs[p] just fully consumed
    }
#undef STAGE_X
#undef STAGE_B

    // ---- K-half merge (deterministic: h=1 writes, h=0 adds once) ----
    __syncthreads();
    f32x16* part  = (f32x16*)&xs[0][0][0][0];  // [2m][2t][64 lanes], 16 KiB
    float4* cand2 = (float4*)&bs[0][0];        // [64 tokens] (p1,p2,E1,E2)

    if (h == 1) {
        part[(m * 2 + 0) * 64 + lane] = acc0;
        part[(m * 2 + 1) * 64 + lane] = acc1;
    }
    __syncthreads();

    if (h == 0) {
        const f32x16 f0 = acc0 + part[(m * 2 + 0) * 64 + lane];
        const f32x16 f1 = acc1 + part[(m * 2 + 1) * 64 + lane];

        // C layout (m74/m101): token row = (i&3)+8*(i>>2)+4*g, expert = 32t+rw.
        // Reduce over the 32-lane col group (masks 1..16 keep g fixed).
#define INS(v, e)                                                              \
        do {                                                                   \
            const float _v = (v); const int _e = (e);                          \
            if (_v > V1 || (_v == V1 && _e < E1)) {                            \
                V2 = V1; E2 = E1; V1 = _v; E1 = _e;                            \
            } else if (_v > V2 || (_v == V2 && _e < E2)) {                     \
                V2 = _v; E2 = _e;                                              \
            }                                                                  \
        } while (0)

#pragma unroll
        for (int i = 0; i < 16; ++i) {
            const int row_i = (i & 3) + 8 * (i >> 2) + 4 * g;
            float V1 = f0[i]; int E1 = rw;
            float V2 = -INFINITY; int E2 = NEXP;
            INS(f1[i], 32 + rw);
#pragma unroll
            for (int mk = 1; mk <= 16; mk <<= 1) {
                const float pv1 = __shfl_xor(V1, mk, 64);
                const int   pe1 = __shfl_xor(E1, mk, 64);
                const float pv2 = __shfl_xor(V2, mk, 64);
                const int   pe2 = __shfl_xor(E2, mk, 64);
                INS(pv1, pe1);
                INS(pv2, pe2);
            }
            if (rw == 0) {
                const float et = expf(V2 - V1);
                float4 c2;
                c2.x = 1.f / (1.f + et);
                c2.y = et / (1.f + et);
                c2.z = __int_as_float(E1);
                c2.w = __int_as_float(E2);
                cand2[32 * m + row_i] = c2;
            }
        }
#undef INS
    }
    __syncthreads();

    // ---- coalesced output: 64 tokens x 16 quads = 1024 float4 (4/thread) ----
#pragma unroll
    for (int jj = 0; jj < 4; ++jj) {
        const int G = jj * NTHREADS + tid;     // 0..1023
        const int tt = G >> 4, q = G & 15;
        const float4 c = cand2[tt];
        const int E1 = __float_as_int(c.z), E2 = __float_as_int(c.w);
        float4 o;
        float* of = (float*)&o;
#pragma unroll
        for (int ii = 0; ii < 4; ++ii) {
            const int e = 4 * q + ii;
            of[ii] = (e == E1) ? c.x : (e == E2) ? c.y : 0.f;
        }
        *(float4*)(out + (size_t)(tok0 + tt) * NEXP + q * 4) = o;
    }
}

extern "C" void kernel_launch(void* const* d_in, const int* in_sizes, int n_in,
                              void* d_out, int out_size, void* d_ws, size_t ws_size,
                              hipStream_t stream)
{
    const float* x   = (const float*)d_in[0];
    const float* emb = (const float*)d_in[1];
    float* out = (float*)d_out;
    uint4* wsb = (uint4*)d_ws;                   // 384 KiB chunk-contiguous frags

    prepack_kernel<<<32, 256, 0, stream>>>(emb, wsb);

    const int n_tokens = in_sizes[0] / HDIM;     // 32768
    const int nblocks  = n_tokens / TPB;         // 512

    router_kernel<<<nblocks, NTHREADS, 0, stream>>>(x, wsb, out);
}

// Round 22
// 48.648 us; speedup vs baseline: 1.2843x; 1.2843x over previous
//
#include <hip/hip_runtime.h>
#include <math.h>
#include <stdint.h>

// Router: scores = x @ emb^T [32768 x 64] fp32-accurate, top-2 + 2-way softmax.
//
// Error-free split-bf16 MFMA (rounds 9-21): 3 bf16 limbs per fp32 operand,
// 6 limb-product MFMA passes accumulated in fp32 (~3e-7 error).
// Round 20 (44.2us, best) = zero-redundancy 16-tok/wave + K-split x2 + staged
// LDS + counted vmcnt. Round 21's 32x32 shape regressed (TLP halved + 4-way
// A-read bank conflicts) -- reverted. This round: round 20's EXACT machinery
// at TPB=32 -> LDS 40960 B -> 4 independent blocks/CU (grid 1024, dispatch
// slack): every barrier/vmcnt/B-stage stall is covered by 3 sibling blocks
// (round 20 had exactly 2 blocks/CU, zero slack, occupancy 38% vs designed
// 50%). Cost: B L2 stream doubles to 393 MB (+6us L2 service, overlapped).

typedef __attribute__((ext_vector_type(8))) short short8;
typedef __attribute__((ext_vector_type(4))) float f32x4;

constexpr int HDIM = 1024;
constexpr int NEXP = 64;
constexpr int TPB  = 32;            // tokens per block
constexpr int NTHREADS = 256;       // 4 waves = 2 token-tiles x 2 K-halves
constexpr int NITER = 16;           // 32-k chunks per K-half

__device__ __forceinline__ uint32_t cvtpk_bf16(float lo, float hi) {
    uint32_t r;
    asm("v_cvt_pk_bf16_f32 %0, %1, %2" : "=v"(r) : "v"(lo), "v"(hi));
    return r;
}

// RNE 3-limb bf16 split of 8 fp32 values; outputs packed frag words.
__device__ __forceinline__ void split8(const float4& A, const float4& B,
                                       uint32_t w0[4], uint32_t w1[4],
                                       uint32_t w2[4])
{
    const float p[8] = {A.x, A.y, A.z, A.w, B.x, B.y, B.z, B.w};
#pragma unroll
    for (int m = 0; m < 4; ++m) {
        const float lo = p[2 * m], hi = p[2 * m + 1];
        const uint32_t c0 = cvtpk_bf16(lo, hi);
        const float l0 = __uint_as_float(c0 << 16);
        const float h0 = __uint_as_float(c0 & 0xFFFF0000u);
        const float rl = lo - l0, rh = hi - h0;         // exact
        const uint32_t c1 = cvtpk_bf16(rl, rh);
        const float l1 = __uint_as_float(c1 << 16);
        const float h1 = __uint_as_float(c1 & 0xFFFF0000u);
        const uint32_t c2 = cvtpk_bf16(rl - l1, rh - h1);
        w0[m] = c0; w1[m] = c1; w2[m] = c2;
    }
}

__device__ __forceinline__ short8 frag_of(uint32_t a, uint32_t b,
                                          uint32_t c, uint32_t d) {
    union { uint4 u; short8 s; } cv;
    cv.u = make_uint4(a, b, c, d);
    return cv.s;
}
__device__ __forceinline__ short8 frag_of4(const uint4& v) {
    union { uint4 u; short8 s; } cv;
    cv.u = v;
    return cv.s;
}

// prepack (identical layout to rounds 15-20; 32k-chunk ch = c*2+jkk is
// contiguous at wsb[ch*768 + (t*3+limb)*64 + lane]):
__global__ __launch_bounds__(256)
void prepack_kernel(const float* __restrict__ emb, uint4* __restrict__ wsb)
{
    const int f2   = blockIdx.x * 256 + threadIdx.x;   // 0..8191
    const int lane = f2 & 63;
    const int t    = (f2 >> 6) & 3;
    const int jkk  = (f2 >> 8) & 1;
    const int c    = f2 >> 9;
    const int e    = t * 16 + (lane & 15);
    const int k0   = (c * 2 + jkk) * 32 + (lane >> 4) * 8;
    const float4 A = *(const float4*)(emb + (size_t)e * HDIM + k0);
    const float4 B = *(const float4*)(emb + (size_t)e * HDIM + k0 + 4);
    uint32_t w0[4], w1[4], w2[4];
    split8(A, B, w0, w1, w2);
    const int ob = c * 1536 + ((jkk * 4 + t) * 3) * 64 + lane;
    wsb[ob]       = make_uint4(w0[0], w0[1], w0[2], w0[3]);
    wsb[ob + 64]  = make_uint4(w1[0], w1[1], w1[2], w1[3]);
    wsb[ob + 128] = make_uint4(w2[0], w2[1], w2[2], w2[3]);
}

__global__ __launch_bounds__(NTHREADS, 4)
void router_kernel(const float* __restrict__ x,
                   const uint4* __restrict__ wsb,
                   float* __restrict__ out)
{
    // EXACTLY 40960 B -> 4 blocks/CU. Epilogue buffers alias into xs / bs.
    __shared__ float4 xs[2][2][TPB][8];  // 16 KiB [buf][half][token][quad]
    __shared__ uint4  bs[2][768];        // 24 KiB [half][chunk image]

    const int tid  = threadIdx.x;
    const int lane = tid & 63;
    const int W    = tid >> 6;          // wave 0..3
    const int m    = W & 1;             // token tile: tokens [16m, 16m+16)
    const int h    = W >> 1;            // K-half: chunks [16h, 16h+16)
    const int tok0 = blockIdx.x * TPB;
    const int col  = lane & 15;
    const int grp  = lane >> 4;

    // x stage for BOTH halves' chunk C: 512 float4, 2 loads/thread.
    // XOR swizzle (q^(r&7)) folded into global source; LDS dest linear.
#define STAGE_X(P, C)                                                          \
    do {                                                                       \
        _Pragma("unroll")                                                      \
        for (int jj = 0; jj < 2; ++jj) {                                       \
            const int g_  = jj * NTHREADS + tid;                               \
            const int hh_ = g_ >> 8, gg_ = g_ & 255;                           \
            const int r_ = gg_ >> 3, q_ = gg_ & 7;                             \
            const float* src = x + (size_t)(tok0 + r_) * HDIM                  \
                                 + (hh_ * 16 + (C)) * 32                       \
                                 + ((q_ ^ (r_ & 7)) * 4);                      \
            __builtin_amdgcn_global_load_lds(                                  \
                (const __attribute__((address_space(1))) void*)src,            \
                (__attribute__((address_space(3))) void*)&xs[P][hh_][r_][q_],  \
                16, 0, 0);                                                     \
        }                                                                      \
    } while (0)

    // B stage for BOTH halves' chunk C: 1536 uint4, 6 loads/thread.
#define STAGE_B(C)                                                             \
    do {                                                                       \
        _Pragma("unroll")                                                      \
        for (int jj = 0; jj < 6; ++jj) {                                       \
            const int f_  = jj * NTHREADS + tid;                               \
            const int hh_ = (f_ >= 768) ? 1 : 0;                               \
            const int of_ = f_ - hh_ * 768;                                    \
            __builtin_amdgcn_global_load_lds(                                  \
                (const __attribute__((address_space(1))) void*)                \
                    (wsb + (size_t)(hh_ * 16 + (C)) * 768 + of_),              \
                (__attribute__((address_space(3))) void*)&bs[hh_][of_],        \
                16, 0, 0);                                                     \
        }                                                                      \
    } while (0)

    // acc[t]: tokens [16m,+16) x experts [16t,+16), partial over K-half h.
    f32x4 acc[4] = {{0,0,0,0}, {0,0,0,0}, {0,0,0,0}, {0,0,0,0}};

    STAGE_X(0, 0);
    STAGE_B(0);
    STAGE_X(1, 1);

#pragma unroll 1
    for (int c = 0; c < NITER; ++c) {
        // Ledger: top of iter c outstanding = B(c)[6] + X(c+1)[2] ->
        // vmcnt(2) retires B(c) (and older X), keeps X(c+1) in flight.
        if (c < NITER - 1) {
            asm volatile("s_waitcnt vmcnt(2)" ::: "memory");
        } else {
            asm volatile("s_waitcnt vmcnt(0)" ::: "memory");
        }
        __builtin_amdgcn_s_barrier();
        asm volatile("" ::: "memory");

        const int p  = c & 1;
        const int r  = 16 * m + col;
        const int rk = col & 7;
        const float4 a0 = xs[p][h][r][(2 * grp)     ^ rk];
        const float4 a1 = xs[p][h][r][(2 * grp + 1) ^ rk];

        uint32_t wa0[4], wa1[4], wa2[4];
        split8(a0, a1, wa0, wa1, wa2);
        const short8 fA0 = frag_of(wa0[0], wa0[1], wa0[2], wa0[3]);
        const short8 fA1 = frag_of(wa1[0], wa1[1], wa1[2], wa1[3]);
        const short8 fA2 = frag_of(wa2[0], wa2[1], wa2[2], wa2[3]);

#pragma unroll
        for (int t = 0; t < 4; ++t) {
            const int bf = (t * 3) * 64 + lane;
            const short8 fb0 = frag_of4(bs[h][bf]);
            const short8 fb1 = frag_of4(bs[h][bf + 64]);
            const short8 fb2 = frag_of4(bs[h][bf + 128]);

            f32x4 a = acc[t];
            a = __builtin_amdgcn_mfma_f32_16x16x32_bf16(fA2, fb0, a, 0,0,0);
            a = __builtin_amdgcn_mfma_f32_16x16x32_bf16(fA0, fb2, a, 0,0,0);
            a = __builtin_amdgcn_mfma_f32_16x16x32_bf16(fA1, fb1, a, 0,0,0);
            a = __builtin_amdgcn_mfma_f32_16x16x32_bf16(fA1, fb0, a, 0,0,0);
            a = __builtin_amdgcn_mfma_f32_16x16x32_bf16(fA0, fb1, a, 0,0,0);
            a = __builtin_amdgcn_mfma_f32_16x16x32_bf16(fA0, fb0, a, 0,0,0);
            acc[t] = a;
        }

        __builtin_amdgcn_s_barrier();   // all waves done reading bs / xs[p]
        asm volatile("" ::: "memory");
        if (c + 1 < NITER) STAGE_B(c + 1);
        if (c + 2 < NITER) STAGE_X(p, c + 2);   // xs[p] just fully consumed
    }
#undef STAGE_X
#undef STAGE_B

    // ---- K-half merge (deterministic: h=1 writes, h=0 adds once) ----
    __syncthreads();
    f32x4*  part  = (f32x4*)&xs[0][0][0][0];   // [2m][4t][64 lanes], 8 KiB
    float4* cand2 = (float4*)&bs[0][0];        // [32 tokens] (p1,p2,E1,E2)

    if (h == 1) {
#pragma unroll
        for (int t = 0; t < 4; ++t) part[(m * 4 + t) * 64 + lane] = acc[t];
    }
    __syncthreads();

    if (h == 0) {
        f32x4 fin[4];
#pragma unroll
        for (int t = 0; t < 4; ++t)
            fin[t] = acc[t] + part[(m * 4 + t) * 64 + lane];

        // top-2 over all 64 experts; fin[t][i]: token 16m+grp*4+i,
        // expert 16t+col. 16-lane shfl merge, lowest index wins ties.
#define INS(v, e)                                                              \
        do {                                                                   \
            const float _v = (v); const int _e = (e);                          \
            if (_v > V1 || (_v == V1 && _e < E1)) {                            \
                V2 = V1; E2 = E1; V1 = _v; E1 = _e;                            \
            } else if (_v > V2 || (_v == V2 && _e < E2)) {                     \
                V2 = _v; E2 = _e;                                              \
            }                                                                  \
        } while (0)

#pragma unroll
        for (int i = 0; i < 4; ++i) {
            float V1 = fin[0][i]; int E1 = col;
            float V2 = -INFINITY; int E2 = NEXP;
            INS(fin[1][i], 16 + col);
            INS(fin[2][i], 32 + col);
            INS(fin[3][i], 48 + col);
#pragma unroll
            for (int mk = 1; mk <= 8; mk <<= 1) {
                const float pv1 = __shfl_xor(V1, mk, 64);
                const int   pe1 = __shfl_xor(E1, mk, 64);
                const float pv2 = __shfl_xor(V2, mk, 64);
                const int   pe2 = __shfl_xor(E2, mk, 64);
                INS(pv1, pe1);
                INS(pv2, pe2);
            }
            if (col == 0) {
                const float et = expf(V2 - V1);
                float4 c2;
                c2.x = 1.f / (1.f + et);
                c2.y = et / (1.f + et);
                c2.z = __int_as_float(E1);
                c2.w = __int_as_float(E2);
                cand2[16 * m + grp * 4 + i] = c2;
            }
        }
#undef INS
    }
    __syncthreads();

    // ---- coalesced output: 32 tokens x 16 quads = 512 float4 (2/thread) ----
#pragma unroll
    for (int jj = 0; jj < 2; ++jj) {
        const int G = jj * NTHREADS + tid;     // 0..511
        const int tt = G >> 4, q = G & 15;
        const float4 c = cand2[tt];
        const int E1 = __float_as_int(c.z), E2 = __float_as_int(c.w);
        float4 o;
        float* of = (float*)&o;
#pragma unroll
        for (int ii = 0; ii < 4; ++ii) {
            const int e = 4 * q + ii;
            of[ii] = (e == E1) ? c.x : (e == E2) ? c.y : 0.f;
        }
        *(float4*)(out + (size_t)(tok0 + tt) * NEXP + q * 4) = o;
    }
}

extern "C" void kernel_launch(void* const* d_in, const int* in_sizes, int n_in,
                              void* d_out, int out_size, void* d_ws, size_t ws_size,
                              hipStream_t stream)
{
    const float* x   = (const float*)d_in[0];
    const float* emb = (const float*)d_in[1];
    float* out = (float*)d_out;
    uint4* wsb = (uint4*)d_ws;                   // 384 KiB chunk-contiguous frags

    prepack_kernel<<<32, 256, 0, stream>>>(emb, wsb);

    const int n_tokens = in_sizes[0] / HDIM;     // 32768
    const int nblocks  = n_tokens / TPB;         // 1024

    router_kernel<<<nblocks, NTHREADS, 0, stream>>>(x, wsb, out);
}

// Round 23
// 47.166 us; speedup vs baseline: 1.3247x; 1.0314x over previous
//
#include <hip/hip_runtime.h>
#include <math.h>
#include <stdint.h>

// Router: scores = x @ emb^T [32768 x 64] fp32-accurate, top-2 + 2-way softmax.
//
// Error-free split-bf16 MFMA (rounds 9-22): 3 bf16 limbs per fp32 operand,
// 6 limb-product MFMA passes accumulated in fp32 (~3e-7 error).
// Round 20 (44.2us best): TPB=64, K-split x2, staged LDS, counted vmcnt.
// Its 4 token-tile waves per K-half re-read IDENTICAL bs[h] slices -> 4x
// redundant B LDS-reads (3072 of 3584 b128/CU; LDS pipe ~58k of 106k cyc).
// This round, single controlled change: wave = 32 tokens (2 A-frag subtiles)
// x 64 experts x K-half; B-frags loaded ONCE per expert-tile feed BOTH
// subtiles (12 B-reads -> 96 MFMAs). Per-CU LDS reads 3584 -> 2048 (-43%);
// splits/MFMAs/traffic unchanged. TLP 4->2 waves/SIMD (measured cost ~0.5us,
// rounds 19/20). Same swizzle, staging, vmcnt ledger as round 20.

typedef __attribute__((ext_vector_type(8))) short short8;
typedef __attribute__((ext_vector_type(4))) float f32x4;

constexpr int HDIM = 1024;
constexpr int NEXP = 64;
constexpr int TPB  = 64;            // tokens per block
constexpr int NTHREADS = 256;       // 4 waves = 2 token-groups x 2 K-halves
constexpr int NITER = 16;           // 32-k chunks per K-half

__device__ __forceinline__ uint32_t cvtpk_bf16(float lo, float hi) {
    uint32_t r;
    asm("v_cvt_pk_bf16_f32 %0, %1, %2" : "=v"(r) : "v"(lo), "v"(hi));
    return r;
}

// RNE 3-limb bf16 split of 8 fp32 values; outputs packed frag words.
__device__ __forceinline__ void split8(const float4& A, const float4& B,
                                       uint32_t w0[4], uint32_t w1[4],
                                       uint32_t w2[4])
{
    const float p[8] = {A.x, A.y, A.z, A.w, B.x, B.y, B.z, B.w};
#pragma unroll
    for (int m = 0; m < 4; ++m) {
        const float lo = p[2 * m], hi = p[2 * m + 1];
        const uint32_t c0 = cvtpk_bf16(lo, hi);
        const float l0 = __uint_as_float(c0 << 16);
        const float h0 = __uint_as_float(c0 & 0xFFFF0000u);
        const float rl = lo - l0, rh = hi - h0;         // exact
        const uint32_t c1 = cvtpk_bf16(rl, rh);
        const float l1 = __uint_as_float(c1 << 16);
        const float h1 = __uint_as_float(c1 & 0xFFFF0000u);
        const uint32_t c2 = cvtpk_bf16(rl - l1, rh - h1);
        w0[m] = c0; w1[m] = c1; w2[m] = c2;
    }
}

__device__ __forceinline__ short8 frag_of(uint32_t a, uint32_t b,
                                          uint32_t c, uint32_t d) {
    union { uint4 u; short8 s; } cv;
    cv.u = make_uint4(a, b, c, d);
    return cv.s;
}
__device__ __forceinline__ short8 frag_of4(const uint4& v) {
    union { uint4 u; short8 s; } cv;
    cv.u = v;
    return cv.s;
}

// prepack (identical layout to rounds 15-22; 32k-chunk ch = c*2+jkk is
// contiguous at wsb[ch*768 + (t*3+limb)*64 + lane]):
__global__ __launch_bounds__(256)
void prepack_kernel(const float* __restrict__ emb, uint4* __restrict__ wsb)
{
    const int f2   = blockIdx.x * 256 + threadIdx.x;   // 0..8191
    const int lane = f2 & 63;
    const int t    = (f2 >> 6) & 3;
    const int jkk  = (f2 >> 8) & 1;
    const int c    = f2 >> 9;
    const int e    = t * 16 + (lane & 15);
    const int k0   = (c * 2 + jkk) * 32 + (lane >> 4) * 8;
    const float4 A = *(const float4*)(emb + (size_t)e * HDIM + k0);
    const float4 B = *(const float4*)(emb + (size_t)e * HDIM + k0 + 4);
    uint32_t w0[4], w1[4], w2[4];
    split8(A, B, w0, w1, w2);
    const int ob = c * 1536 + ((jkk * 4 + t) * 3) * 64 + lane;
    wsb[ob]       = make_uint4(w0[0], w0[1], w0[2], w0[3]);
    wsb[ob + 64]  = make_uint4(w1[0], w1[1], w1[2], w1[3]);
    wsb[ob + 128] = make_uint4(w2[0], w2[1], w2[2], w2[3]);
}

__global__ __launch_bounds__(NTHREADS, 2)
void router_kernel(const float* __restrict__ x,
                   const uint4* __restrict__ wsb,
                   float* __restrict__ out)
{
    // 57344 B -> 2 blocks/CU. Epilogue buffers alias into xs / bs.
    __shared__ float4 xs[2][2][TPB][8];  // 32 KiB [buf][half][token][quad]
    __shared__ uint4  bs[2][768];        // 24 KiB [half][chunk image]

    const int tid  = threadIdx.x;
    const int lane = tid & 63;
    const int W    = tid >> 6;          // wave 0..3
    const int m    = W & 1;             // token group: tokens [32m, 32m+32)
    const int h    = W >> 1;            // K-half: chunks [16h, 16h+16)
    const int tok0 = blockIdx.x * TPB;
    const int col  = lane & 15;
    const int grp  = lane >> 4;

    // x stage for BOTH halves' chunk C: 1024 float4, 4 loads/thread.
    // XOR swizzle (q^(r&7)) folded into global source; LDS dest linear.
#define STAGE_X(P, C)                                                          \
    do {                                                                       \
        _Pragma("unroll")                                                      \
        for (int jj = 0; jj < 4; ++jj) {                                       \
            const int g_  = jj * NTHREADS + tid;                               \
            const int hh_ = g_ >> 9, gg_ = g_ & 511;                           \
            const int r_ = gg_ >> 3, q_ = gg_ & 7;                             \
            const float* src = x + (size_t)(tok0 + r_) * HDIM                  \
                                 + (hh_ * 16 + (C)) * 32                       \
                                 + ((q_ ^ (r_ & 7)) * 4);                      \
            __builtin_amdgcn_global_load_lds(                                  \
                (const __attribute__((address_space(1))) void*)src,            \
                (__attribute__((address_space(3))) void*)&xs[P][hh_][r_][q_],  \
                16, 0, 0);                                                     \
        }                                                                      \
    } while (0)

    // B stage for BOTH halves' chunk C: 1536 uint4, 6 loads/thread.
#define STAGE_B(C)                                                             \
    do {                                                                       \
        _Pragma("unroll")                                                      \
        for (int jj = 0; jj < 6; ++jj) {                                       \
            const int f_  = jj * NTHREADS + tid;                               \
            const int hh_ = (f_ >= 768) ? 1 : 0;                               \
            const int of_ = f_ - hh_ * 768;                                    \
            __builtin_amdgcn_global_load_lds(                                  \
                (const __attribute__((address_space(1))) void*)                \
                    (wsb + (size_t)(hh_ * 16 + (C)) * 768 + of_),              \
                (__attribute__((address_space(3))) void*)&bs[hh_][of_],        \
                16, 0, 0);                                                     \
        }                                                                      \
    } while (0)

    // acc[s][t]: tokens [32m+16s,+16) x experts [16t,+16), partial over half h.
    f32x4 acc[2][4] = {{{0,0,0,0},{0,0,0,0},{0,0,0,0},{0,0,0,0}},
                       {{0,0,0,0},{0,0,0,0},{0,0,0,0},{0,0,0,0}}};

    STAGE_X(0, 0);
    STAGE_B(0);
    STAGE_X(1, 1);

#pragma unroll 1
    for (int c = 0; c < NITER; ++c) {
        // Ledger: top of iter c outstanding = B(c)[6] + X(c+1)[4] ->
        // vmcnt(4) retires B(c) (and older X), keeps X(c+1) in flight.
        if (c < NITER - 1) {
            asm volatile("s_waitcnt vmcnt(4)" ::: "memory");
        } else {
            asm volatile("s_waitcnt vmcnt(0)" ::: "memory");
        }
        __builtin_amdgcn_s_barrier();
        asm volatile("" ::: "memory");

        const int p  = c & 1;
        const int rk = col & 7;

        // split both token-subtiles' A-frags first (4 ds_reads + 2 split8)
        short8 fA[2][3];
#pragma unroll
        for (int s = 0; s < 2; ++s) {
            const int r = 32 * m + 16 * s + col;
            const float4 a0 = xs[p][h][r][(2 * grp)     ^ rk];
            const float4 a1 = xs[p][h][r][(2 * grp + 1) ^ rk];
            uint32_t wa0[4], wa1[4], wa2[4];
            split8(a0, a1, wa0, wa1, wa2);
            fA[s][0] = frag_of(wa0[0], wa0[1], wa0[2], wa0[3]);
            fA[s][1] = frag_of(wa1[0], wa1[1], wa1[2], wa1[3]);
            fA[s][2] = frag_of(wa2[0], wa2[1], wa2[2], wa2[3]);
        }

        // B-frags loaded once per expert-tile, feed BOTH subtiles (12 MFMA/t)
#pragma unroll
        for (int t = 0; t < 4; ++t) {
            const int bf = (t * 3) * 64 + lane;
            const short8 fb0 = frag_of4(bs[h][bf]);
            const short8 fb1 = frag_of4(bs[h][bf + 64]);
            const short8 fb2 = frag_of4(bs[h][bf + 128]);

#pragma unroll
            for (int s = 0; s < 2; ++s) {
                f32x4 a = acc[s][t];
                a = __builtin_amdgcn_mfma_f32_16x16x32_bf16(fA[s][2], fb0, a, 0,0,0);
                a = __builtin_amdgcn_mfma_f32_16x16x32_bf16(fA[s][0], fb2, a, 0,0,0);
                a = __builtin_amdgcn_mfma_f32_16x16x32_bf16(fA[s][1], fb1, a, 0,0,0);
                a = __builtin_amdgcn_mfma_f32_16x16x32_bf16(fA[s][1], fb0, a, 0,0,0);
                a = __builtin_amdgcn_mfma_f32_16x16x32_bf16(fA[s][0], fb1, a, 0,0,0);
                a = __builtin_amdgcn_mfma_f32_16x16x32_bf16(fA[s][0], fb0, a, 0,0,0);
                acc[s][t] = a;
            }
        }

        __builtin_amdgcn_s_barrier();   // all waves done reading bs / xs[p]
        asm volatile("" ::: "memory");
        if (c + 1 < NITER) STAGE_B(c + 1);
        if (c + 2 < NITER) STAGE_X(p, c + 2);   // xs[p] just fully consumed
    }
#undef STAGE_X
#undef STAGE_B

    // ---- K-half merge (deterministic: h=1 writes, h=0 adds once) ----
    __syncthreads();
    f32x4*  part  = (f32x4*)&xs[0][0][0][0];   // [2m][8 acc][64 lanes], 16 KiB
    float4* cand2 = (float4*)&bs[0][0];        // [64 tokens] (p1,p2,E1,E2)

    if (h == 1) {
#pragma unroll
        for (int s = 0; s < 2; ++s)
#pragma unroll
            for (int t = 0; t < 4; ++t)
                part[(m * 8 + s * 4 + t) * 64 + lane] = acc[s][t];
    }
    __syncthreads();

    if (h == 0) {
        f32x4 fin[2][4];
#pragma unroll
        for (int s = 0; s < 2; ++s)
#pragma unroll
            for (int t = 0; t < 4; ++t)
                fin[s][t] = acc[s][t] + part[(m * 8 + s * 4 + t) * 64 + lane];

        // top-2 over all 64 experts; fin[s][t][i]: token 32m+16s+grp*4+i,
        // expert 16t+col. 16-lane shfl merge, lowest index wins ties.
#define INS(v, e)                                                              \
        do {                                                                   \
            const float _v = (v); const int _e = (e);                          \
            if (_v > V1 || (_v == V1 && _e < E1)) {                            \
                V2 = V1; E2 = E1; V1 = _v; E1 = _e;                            \
            } else if (_v > V2 || (_v == V2 && _e < E2)) {                     \
                V2 = _v; E2 = _e;                                              \
            }                                                                  \
        } while (0)

#pragma unroll
        for (int s = 0; s < 2; ++s) {
#pragma unroll
            for (int i = 0; i < 4; ++i) {
                float V1 = fin[s][0][i]; int E1 = col;
                float V2 = -INFINITY; int E2 = NEXP;
                INS(fin[s][1][i], 16 + col);
                INS(fin[s][2][i], 32 + col);
                INS(fin[s][3][i], 48 + col);
#pragma unroll
                for (int mk = 1; mk <= 8; mk <<= 1) {
                    const float pv1 = __shfl_xor(V1, mk, 64);
                    const int   pe1 = __shfl_xor(E1, mk, 64);
                    const float pv2 = __shfl_xor(V2, mk, 64);
                    const int   pe2 = __shfl_xor(E2, mk, 64);
                    INS(pv1, pe1);
                    INS(pv2, pe2);
                }
                if (col == 0) {
                    const float et = expf(V2 - V1);
                    float4 c2;
                    c2.x = 1.f / (1.f + et);
                    c2.y = et / (1.f + et);
                    c2.z = __int_as_float(E1);
                    c2.w = __int_as_float(E2);
                    cand2[32 * m + 16 * s + grp * 4 + i] = c2;
                }
            }
        }
#undef INS
    }
    __syncthreads();

    // ---- coalesced output: 64 tokens x 16 quads = 1024 float4 (4/thread) ----
#pragma unroll
    for (int jj = 0; jj < 4; ++jj) {
        const int G = jj * NTHREADS + tid;     // 0..1023
        const int tt = G >> 4, q = G & 15;
        const float4 c = cand2[tt];
        const int E1 = __float_as_int(c.z), E2 = __float_as_int(c.w);
        float4 o;
        float* of = (float*)&o;
#pragma unroll
        for (int ii = 0; ii < 4; ++ii) {
            const int e = 4 * q + ii;
            of[ii] = (e == E1) ? c.x : (e == E2) ? c.y : 0.f;
        }
        *(float4*)(out + (size_t)(tok0 + tt) * NEXP + q * 4) = o;
    }
}

extern "C" void kernel_launch(void* const* d_in, const int* in_sizes, int n_in,
                              void* d_out, int out_size, void* d_ws, size_t ws_size,
                              hipStream_t stream)
{
    const float* x   = (const float*)d_in[0];
    const float* emb = (const float*)d_in[1];
    float* out = (float*)d_out;
    uint4* wsb = (uint4*)d_ws;                   // 384 KiB chunk-contiguous frags

    prepack_kernel<<<32, 256, 0, stream>>>(emb, wsb);

    const int n_tokens = in_sizes[0] / HDIM;     // 32768
    const int nblocks  = n_tokens / TPB;         // 512

    router_kernel<<<nblocks, NTHREADS, 0, stream>>>(x, wsb, out);
}

// Round 24
// 43.879 us; speedup vs baseline: 1.4239x; 1.0749x over previous
//
#include <hip/hip_runtime.h>
#include <math.h>
#include <stdint.h>

// Router: scores = x @ emb^T [32768 x 64] fp32-accurate, top-2 + 2-way softmax.
//
// FINAL (round 20, session best 44.2us): error-free split-bf16 MFMA -- 3 bf16
// limbs per fp32 operand (RNE, exact residuals), 6 limb-product MFMA passes
// accumulated in fp32 (~3e-7 score error, passes the 0.0039 absmax bar).
// Structure: zero-redundancy wave = 16 tok x 64 exp x K-half; block = 512 thr
// = 4 token-tiles x 2 K-halves; 32-k chunks, x+B DMA-staged via
// global_load_lds (linear dest, XOR-swizzled source -> 0 bank conflicts),
// double-buffered x, per-half B buffers, counted vmcnt(2), deterministic
// K-half LDS merge, 16-lane shfl top-2 (lowest-index ties = jax.lax.top_k),
// closed-form 2-way softmax, coalesced float4 output.
// Session ledger: redundancy-kill was the decisive lever (61.7->44.7, r19);
// TLP/ILP/vmcnt/tile/shape/sharing moves all null or regressed (r10-r23).

typedef __attribute__((ext_vector_type(8))) short short8;
typedef __attribute__((ext_vector_type(4))) float f32x4;

constexpr int HDIM = 1024;
constexpr int NEXP = 64;
constexpr int TPB  = 64;            // tokens per block
constexpr int NTHREADS = 512;       // 8 waves
constexpr int NITER = 16;           // 32-k steps per K-half

__device__ __forceinline__ uint32_t cvtpk_bf16(float lo, float hi) {
    uint32_t r;
    asm("v_cvt_pk_bf16_f32 %0, %1, %2" : "=v"(r) : "v"(lo), "v"(hi));
    return r;
}

// RNE 3-limb bf16 split of 8 fp32 values; outputs packed frag words.
__device__ __forceinline__ void split8(const float4& A, const float4& B,
                                       uint32_t w0[4], uint32_t w1[4],
                                       uint32_t w2[4])
{
    const float p[8] = {A.x, A.y, A.z, A.w, B.x, B.y, B.z, B.w};
#pragma unroll
    for (int m = 0; m < 4; ++m) {
        const float lo = p[2 * m], hi = p[2 * m + 1];
        const uint32_t c0 = cvtpk_bf16(lo, hi);
        const float l0 = __uint_as_float(c0 << 16);
        const float h0 = __uint_as_float(c0 & 0xFFFF0000u);
        const float rl = lo - l0, rh = hi - h0;         // exact
        const uint32_t c1 = cvtpk_bf16(rl, rh);
        const float l1 = __uint_as_float(c1 << 16);
        const float h1 = __uint_as_float(c1 & 0xFFFF0000u);
        const uint32_t c2 = cvtpk_bf16(rl - l1, rh - h1);
        w0[m] = c0; w1[m] = c1; w2[m] = c2;
    }
}

__device__ __forceinline__ short8 frag_of(uint32_t a, uint32_t b,
                                          uint32_t c, uint32_t d) {
    union { uint4 u; short8 s; } cv;
    cv.u = make_uint4(a, b, c, d);
    return cv.s;
}
__device__ __forceinline__ short8 frag_of4(const uint4& v) {
    union { uint4 u; short8 s; } cv;
    cv.u = v;
    return cv.s;
}

// prepack (32k-chunk ch = c*2+jkk contiguous at wsb[ch*768+(t*3+limb)*64+lane]):
__global__ __launch_bounds__(256)
void prepack_kernel(const float* __restrict__ emb, uint4* __restrict__ wsb)
{
    const int f2   = blockIdx.x * 256 + threadIdx.x;   // 0..8191
    const int lane = f2 & 63;
    const int t    = (f2 >> 6) & 3;
    const int jkk  = (f2 >> 8) & 1;
    const int c    = f2 >> 9;
    const int e    = t * 16 + (lane & 15);
    const int k0   = (c * 2 + jkk) * 32 + (lane >> 4) * 8;
    const float4 A = *(const float4*)(emb + (size_t)e * HDIM + k0);
    const float4 B = *(const float4*)(emb + (size_t)e * HDIM + k0 + 4);
    uint32_t w0[4], w1[4], w2[4];
    split8(A, B, w0, w1, w2);
    const int ob = c * 1536 + ((jkk * 4 + t) * 3) * 64 + lane;
    wsb[ob]       = make_uint4(w0[0], w0[1], w0[2], w0[3]);
    wsb[ob + 64]  = make_uint4(w1[0], w1[1], w1[2], w1[3]);
    wsb[ob + 128] = make_uint4(w2[0], w2[1], w2[2], w2[3]);
}

__global__ __launch_bounds__(NTHREADS, 4)
void router_kernel(const float* __restrict__ x,
                   const uint4* __restrict__ wsb,
                   float* __restrict__ out)
{
    // 57344 B total -> 2 blocks/CU. Epilogue aliases into xs / bs.
    __shared__ float4 xs[2][2][TPB][8];  // 32 KiB, [buf][half][token][quad^]
    __shared__ uint4  bs[2][768];        // 24 KiB, [half][staged B chunk]

    const int tid  = threadIdx.x;
    const int lane = tid & 63;
    const int W    = tid >> 6;          // wave 0..7
    const int m    = W & 3;             // token tile: tokens [16m, 16m+16)
    const int h    = W >> 2;            // K-half: chunks [16h, 16h+16)
    const int tok0 = blockIdx.x * TPB;
    const int col  = lane & 15;
    const int grp  = lane >> 4;

    // x stage for BOTH halves' chunk C: 1024 float4, 2 loads/thread.
    // XOR swizzle (q^(r&7)) folded into global source; LDS dest linear.
#define STAGE_X(P, C)                                                          \
    do {                                                                       \
        _Pragma("unroll")                                                      \
        for (int jj = 0; jj < 2; ++jj) {                                       \
            const int g_  = jj * NTHREADS + tid;                               \
            const int hh_ = g_ >> 9, gg_ = g_ & 511;                           \
            const int r_ = gg_ >> 3, q_ = gg_ & 7;                             \
            const float* src = x + (size_t)(tok0 + r_) * HDIM                  \
                                 + (hh_ * 16 + (C)) * 32                       \
                                 + ((q_ ^ (r_ & 7)) * 4);                      \
            __builtin_amdgcn_global_load_lds(                                  \
                (const __attribute__((address_space(1))) void*)src,            \
                (__attribute__((address_space(3))) void*)&xs[P][hh_][r_][q_],  \
                16, 0, 0);                                                     \
        }                                                                      \
    } while (0)

    // B stage for BOTH halves' chunk C: 1536 uint4, 3 loads/thread.
#define STAGE_B(C)                                                             \
    do {                                                                       \
        _Pragma("unroll")                                                      \
        for (int jj = 0; jj < 3; ++jj) {                                       \
            const int f_  = jj * NTHREADS + tid;                               \
            const int hh_ = (f_ >= 768) ? 1 : 0;                               \
            const int of_ = f_ - hh_ * 768;                                    \
            __builtin_amdgcn_global_load_lds(                                  \
                (const __attribute__((address_space(1))) void*)                \
                    (wsb + (size_t)hh_ * 12288 + (C) * 768 + of_),             \
                (__attribute__((address_space(3))) void*)&bs[hh_][of_],        \
                16, 0, 0);                                                     \
        }                                                                      \
    } while (0)

    // wave-local accumulators: acc[t] = tokens [16m,+16) x experts [16t,+16),
    // partial over this wave's K-half.
    f32x4 acc[4] = {{0,0,0,0}, {0,0,0,0}, {0,0,0,0}, {0,0,0,0}};

    STAGE_X(0, 0);
    STAGE_B(0);
    STAGE_X(1, 1);

#pragma unroll 1
    for (int c = 0; c < NITER; ++c) {
        // Ledger: top of iter c outstanding = B(c)[3] + X(c+1)[2] ->
        // vmcnt(2) retires B(c) (and older), keeps X(c+1) in flight.
        if (c < NITER - 1) {
            asm volatile("s_waitcnt vmcnt(2)" ::: "memory");
        } else {
            asm volatile("s_waitcnt vmcnt(0)" ::: "memory");
        }
        __builtin_amdgcn_s_barrier();
        asm volatile("" ::: "memory");

        const int p  = c & 1;
        const int r  = 16 * m + col;
        const int rk = col & 7;
        const float4 a0 = xs[p][h][r][(2 * grp)     ^ rk];
        const float4 a1 = xs[p][h][r][(2 * grp + 1) ^ rk];

        uint32_t wa0[4], wa1[4], wa2[4];
        split8(a0, a1, wa0, wa1, wa2);
        const short8 fA0 = frag_of(wa0[0], wa0[1], wa0[2], wa0[3]);
        const short8 fA1 = frag_of(wa1[0], wa1[1], wa1[2], wa1[3]);
        const short8 fA2 = frag_of(wa2[0], wa2[1], wa2[2], wa2[3]);

#pragma unroll
        for (int t = 0; t < 4; ++t) {
            const int bf = (t * 3) * 64 + lane;
            const short8 fb0 = frag_of4(bs[h][bf]);
            const short8 fb1 = frag_of4(bs[h][bf + 64]);
            const short8 fb2 = frag_of4(bs[h][bf + 128]);

            f32x4 a = acc[t];
            a = __builtin_amdgcn_mfma_f32_16x16x32_bf16(fA2, fb0, a, 0,0,0);
            a = __builtin_amdgcn_mfma_f32_16x16x32_bf16(fA0, fb2, a, 0,0,0);
            a = __builtin_amdgcn_mfma_f32_16x16x32_bf16(fA1, fb1, a, 0,0,0);
            a = __builtin_amdgcn_mfma_f32_16x16x32_bf16(fA1, fb0, a, 0,0,0);
            a = __builtin_amdgcn_mfma_f32_16x16x32_bf16(fA0, fb1, a, 0,0,0);
            a = __builtin_amdgcn_mfma_f32_16x16x32_bf16(fA0, fb0, a, 0,0,0);
            acc[t] = a;
        }

        __builtin_amdgcn_s_barrier();   // all waves done reading bs / xs[p]
        asm volatile("" ::: "memory");
        if (c + 1 < NITER) STAGE_B(c + 1);
        if (c + 2 < NITER) STAGE_X(p, c + 2);   // xs[p] just fully consumed
    }
#undef STAGE_X
#undef STAGE_B

    // ---- K-half merge (deterministic: h=1 writes, h=0 adds once) ----
    __syncthreads();
    f32x4*  part  = (f32x4*)&xs[0][0][0][0];   // [m][t][lane], 16 KiB
    float4* cand2 = (float4*)&bs[0][0];        // [64 tokens] (p1,p2,E1,E2)

    if (h == 1) {
#pragma unroll
        for (int t = 0; t < 4; ++t) part[(m * 4 + t) * 64 + lane] = acc[t];
    }
    __syncthreads();

    if (h == 0) {
        f32x4 fin[4];
#pragma unroll
        for (int t = 0; t < 4; ++t)
            fin[t] = acc[t] + part[(m * 4 + t) * 64 + lane];

        // top-2 over all 64 experts; fin[t][i]: token 16m+grp*4+i,
        // expert 16t+col. 16-lane shfl merge, lowest index wins ties.
#define INS(v, e)                                                              \
        do {                                                                   \
            const float _v = (v); const int _e = (e);                          \
            if (_v > V1 || (_v == V1 && _e < E1)) {                            \
                V2 = V1; E2 = E1; V1 = _v; E1 = _e;                            \
            } else if (_v > V2 || (_v == V2 && _e < E2)) {                     \
                V2 = _v; E2 = _e;                                              \
            }                                                                  \
        } while (0)

#pragma unroll
        for (int i = 0; i < 4; ++i) {
            float V1 = fin[0][i]; int E1 = col;
            float V2 = -INFINITY; int E2 = NEXP;
            INS(fin[1][i], 16 + col);
            INS(fin[2][i], 32 + col);
            INS(fin[3][i], 48 + col);
#pragma unroll
            for (int mk = 1; mk <= 8; mk <<= 1) {
                const float pv1 = __shfl_xor(V1, mk, 64);
                const int   pe1 = __shfl_xor(E1, mk, 64);
                const float pv2 = __shfl_xor(V2, mk, 64);
                const int   pe2 = __shfl_xor(E2, mk, 64);
                INS(pv1, pe1);
                INS(pv2, pe2);
            }
            if (col == 0) {
                const float et = expf(V2 - V1);
                float4 c2;
                c2.x = 1.f / (1.f + et);
                c2.y = et / (1.f + et);
                c2.z = __int_as_float(E1);
                c2.w = __int_as_float(E2);
                cand2[16 * m + grp * 4 + i] = c2;
            }
        }
#undef INS
    }
    __syncthreads();

    // ---- coalesced output: 64 tokens x 16 quads = 1024 float4 (2/thread) ----
#pragma unroll
    for (int jj = 0; jj < 2; ++jj) {
        const int G = jj * NTHREADS + tid;     // 0..1023
        const int tt = G >> 4, q = G & 15;
        const float4 c = cand2[tt];
        const int E1 = __float_as_int(c.z), E2 = __float_as_int(c.w);
        float4 o;
        float* of = (float*)&o;
#pragma unroll
        for (int ii = 0; ii < 4; ++ii) {
            const int e = 4 * q + ii;
            of[ii] = (e == E1) ? c.x : (e == E2) ? c.y : 0.f;
        }
        *(float4*)(out + (size_t)(tok0 + tt) * NEXP + q * 4) = o;
    }
}

extern "C" void kernel_launch(void* const* d_in, const int* in_sizes, int n_in,
                              void* d_out, int out_size, void* d_ws, size_t ws_size,
                              hipStream_t stream)
{
    const float* x   = (const float*)d_in[0];
    const float* emb = (const float*)d_in[1];
    float* out = (float*)d_out;
    uint4* wsb = (uint4*)d_ws;                   // 384 KiB chunk-contiguous frags

    prepack_kernel<<<32, 256, 0, stream>>>(emb, wsb);

    const int n_tokens = in_sizes[0] / HDIM;     // 32768
    const int nblocks  = n_tokens / TPB;         // 512

    router_kernel<<<nblocks, NTHREADS, 0, stream>>>(x, wsb, out);
}